// Round 1
// baseline (892.185 us; speedup 1.0000x reference)
//
#include <hip/hip_runtime.h>
#include <hip/hip_fp16.h>

typedef _Float16 f16x4 __attribute__((ext_vector_type(4)));
typedef _Float16 f16x8 __attribute__((ext_vector_type(8)));
typedef float    f32x4 __attribute__((ext_vector_type(4)));

#define TBD 67108864ull   // T*B*D
#define BD  1048576ull    // B*D
#define M_DIM 65536       // T*B

// ---------------- Kernel 1: se = (pred-true)^2, split into fp16 hi/lo ----------------
__global__ __launch_bounds__(256) void se_split_k(const float* __restrict__ pred,
                                                  const float* __restrict__ tru,
                                                  _Float16* __restrict__ hi,
                                                  _Float16* __restrict__ lo) {
  size_t stride = (size_t)gridDim.x * 1024;
  for (size_t i = ((size_t)blockIdx.x * 256 + threadIdx.x) * 4; i < TBD; i += stride) {
    float4 p = *(const float4*)(pred + i);
    float4 t = *(const float4*)(tru + i);
    float s0 = (p.x - t.x) * (p.x - t.x);
    float s1 = (p.y - t.y) * (p.y - t.y);
    float s2 = (p.z - t.z) * (p.z - t.z);
    float s3 = (p.w - t.w) * (p.w - t.w);
    f16x4 h, l;
    h[0] = (_Float16)s0; l[0] = (_Float16)(s0 - (float)h[0]);
    h[1] = (_Float16)s1; l[1] = (_Float16)(s1 - (float)h[1]);
    h[2] = (_Float16)s2; l[2] = (_Float16)(s2 - (float)h[2]);
    h[3] = (_Float16)s3; l[3] = (_Float16)(s3 - (float)h[3]);
    *(f16x4*)(hi + i) = h;
    *(f16x4*)(lo + i) = l;
  }
}

// ---------------- Kernel 2: split W into fp16 hi/lo ----------------
__global__ __launch_bounds__(256) void w_split_k(const float* __restrict__ W,
                                                 _Float16* __restrict__ hi,
                                                 _Float16* __restrict__ lo) {
  size_t i = ((size_t)blockIdx.x * 256 + threadIdx.x) * 4;  // covers 1048576 exactly
  float4 x = *(const float4*)(W + i);
  f16x4 h, l;
  h[0] = (_Float16)x.x; l[0] = (_Float16)(x.x - (float)h[0]);
  h[1] = (_Float16)x.y; l[1] = (_Float16)(x.y - (float)h[1]);
  h[2] = (_Float16)x.z; l[2] = (_Float16)(x.z - (float)h[2]);
  h[3] = (_Float16)x.w; l[3] = (_Float16)(x.w - (float)h[3]);
  *(f16x4*)(hi + i) = h;
  *(f16x4*)(lo + i) = l;
}

// ---------------- Kernel 3: logits = SE @ W^T + b  (split-fp16 3-pass MFMA) ----------------
// M=65536, N=1024, K=1024. A (se) [M,K] row-major hi/lo; W [N,K] row-major hi/lo (B^T GEMM).
// Tile 128x128, BK=32, 4 waves (2x2), each wave 64x64 = 4x4 frags of 16x16.
// LDS: A-tile [128 rows][8 slots of 16B] = hi(slots 0-3)|lo(slots 4-7), XOR-swizzled slot^=(row&7).
__global__ __launch_bounds__(256) void gemm_logits_k(
    const _Float16* __restrict__ Ah, const _Float16* __restrict__ Al,
    const _Float16* __restrict__ Wh, const _Float16* __restrict__ Wl,
    const float* __restrict__ bias, float* __restrict__ C) {
  __shared__ uint4 lds4[2048];  // 32 KB: A region [0,16384), B region [16384,32768)
  char* lds = (char*)lds4;
  const int tid = threadIdx.x;
  const int lane = tid & 63;
  const int wid = tid >> 6;
  const int wr = wid >> 1, wc = wid & 1;

  // XCD-aware bijective swizzle (4096 blocks, 8 XCDs)
  const int bid = blockIdx.x;
  const int wgid = (bid & 7) * 512 + (bid >> 3);
  const int bm = wgid >> 3, bn = wgid & 7;
  const int row0 = bm * 128, col0 = bn * 128;

  // Staging: per thread 4 x 16B chunks per tile. Linear LDS dest, inverse-swizzled source.
  const _Float16* srcA[4];
  const _Float16* srcB[4];
  int ldsA[4], ldsB[4];
#pragma unroll
  for (int q = 0; q < 4; ++q) {
    int p = q * 4096 + tid * 16;      // byte offset in tile region
    int r = p >> 7;                   // tile row (128B per row)
    int s = (p >> 4) & 7;             // physical 16B slot
    int sig = s ^ (r & 7);            // logical slot (XOR involution)
    size_t koff = (size_t)(sig & 3) * 8;
    srcA[q] = (sig < 4 ? Ah : Al) + ((size_t)(row0 + r) * 1024 + koff);
    srcB[q] = (sig < 4 ? Wh : Wl) + ((size_t)(col0 + r) * 1024 + koff);
    ldsA[q] = p;
    ldsB[q] = 16384 + p;
  }

  // Fragment read offsets (swizzled)
  const int u = lane >> 4;          // 0..3
  const int sw = lane & 7;
  const int rA = wr * 64 + (lane & 15);
  const int rB = wc * 64 + (lane & 15);
  const int aoff_h = rA * 128 + ((u)     ^ sw) * 16;
  const int aoff_l = rA * 128 + ((u + 4) ^ sw) * 16;
  const int boff_h = 16384 + rB * 128 + ((u)     ^ sw) * 16;
  const int boff_l = 16384 + rB * 128 + ((u + 4) ^ sw) * 16;

  f32x4 acc[4][4] = {};

#pragma unroll 2
  for (int kk = 0; kk < 32; ++kk) {
    __syncthreads();  // previous compute done before overwrite
#pragma unroll
    for (int q = 0; q < 4; ++q) {
      __builtin_amdgcn_global_load_lds(
          (const __attribute__((address_space(1))) void*)(srcA[q]),
          (__attribute__((address_space(3))) void*)(lds + ldsA[q]), 16, 0, 0);
      __builtin_amdgcn_global_load_lds(
          (const __attribute__((address_space(1))) void*)(srcB[q]),
          (__attribute__((address_space(3))) void*)(lds + ldsB[q]), 16, 0, 0);
      srcA[q] += 32;
      srcB[q] += 32;
    }
    asm volatile("s_waitcnt vmcnt(0)" ::: "memory");
    __syncthreads();

    f16x8 ah[4], al[4];
#pragma unroll
    for (int fi = 0; fi < 4; ++fi) {
      ah[fi] = *(const f16x8*)(lds + aoff_h + fi * 2048);
      al[fi] = *(const f16x8*)(lds + aoff_l + fi * 2048);
    }
#pragma unroll
    for (int fj = 0; fj < 4; ++fj) {
      f16x8 bh = *(const f16x8*)(lds + boff_h + fj * 2048);
      f16x8 bl = *(const f16x8*)(lds + boff_l + fj * 2048);
#pragma unroll
      for (int fi = 0; fi < 4; ++fi) {
        acc[fi][fj] = __builtin_amdgcn_mfma_f32_16x16x32_f16(ah[fi], bh, acc[fi][fj], 0, 0, 0);
        acc[fi][fj] = __builtin_amdgcn_mfma_f32_16x16x32_f16(al[fi], bh, acc[fi][fj], 0, 0, 0);
        acc[fi][fj] = __builtin_amdgcn_mfma_f32_16x16x32_f16(ah[fi], bl, acc[fi][fj], 0, 0, 0);
      }
    }
  }

  // Epilogue: C[i,j] = acc + bias[j].  C/D layout: col=lane&15, row=(lane>>4)*4+q.
#pragma unroll
  for (int fj = 0; fj < 4; ++fj) {
    int c = col0 + wc * 64 + fj * 16 + (lane & 15);
    float bj = bias[c];
#pragma unroll
    for (int fi = 0; fi < 4; ++fi) {
      int r = row0 + wr * 64 + fi * 16 + u * 4;
#pragma unroll
      for (int q = 0; q < 4; ++q)
        C[(size_t)(r + q) * 1024 + c] = acc[fi][fj][q] + bj;
    }
  }
}

// ---------------- Kernel 4: row softmax + weight = se * softmax(logits), in-place ----------------
__global__ __launch_bounds__(256) void softmax_w_k(float* __restrict__ logits,
                                                   const _Float16* __restrict__ hi,
                                                   const _Float16* __restrict__ lo) {
  const int row = blockIdx.x;            // 0..65535 (t*B+b)
  const size_t base = (size_t)row * 1024;
  const int tid = threadIdx.x, lane = tid & 63, wid = tid >> 6;
  float4 x = ((const float4*)(logits + base))[tid];
  float m = fmaxf(fmaxf(x.x, x.y), fmaxf(x.z, x.w));
#pragma unroll
  for (int o = 32; o >= 1; o >>= 1) m = fmaxf(m, __shfl_xor(m, o, 64));
  __shared__ float red[8];
  if (lane == 0) red[wid] = m;
  __syncthreads();
  m = fmaxf(fmaxf(red[0], red[1]), fmaxf(red[2], red[3]));
  float e0 = __expf(x.x - m), e1 = __expf(x.y - m), e2 = __expf(x.z - m), e3 = __expf(x.w - m);
  float s = (e0 + e1) + (e2 + e3);
#pragma unroll
  for (int o = 32; o >= 1; o >>= 1) s += __shfl_xor(s, o, 64);
  if (lane == 0) red[4 + wid] = s;
  __syncthreads();
  s = (red[4] + red[5]) + (red[6] + red[7]);
  float inv = 1.0f / s;
  f16x4 h = ((const f16x4*)(hi + base))[tid];
  f16x4 l = ((const f16x4*)(lo + base))[tid];
  float4 w;
  w.x = ((float)h[0] + (float)l[0]) * e0 * inv;
  w.y = ((float)h[1] + (float)l[1]) * e1 * inv;
  w.z = ((float)h[2] + (float)l[2]) * e2 * inv;
  w.w = ((float)h[3] + (float)l[3]) * e3 * inv;
  ((float4*)(logits + base))[tid] = w;
}

// ---------------- Kernel 5: loss[b,d] = se_0 + sum_{t=1..63} w_{t-1} * se_t ----------------
__global__ __launch_bounds__(256) void loss_k(const _Float16* __restrict__ hi,
                                              const _Float16* __restrict__ lo,
                                              const float* __restrict__ w,
                                              float* __restrict__ out) {
  size_t i = ((size_t)blockIdx.x * 256 + threadIdx.x) * 4;  // over B*D
  f16x4 h = *(const f16x4*)(hi + i);
  f16x4 l = *(const f16x4*)(lo + i);
  float4 a;
  a.x = (float)h[0] + (float)l[0];
  a.y = (float)h[1] + (float)l[1];
  a.z = (float)h[2] + (float)l[2];
  a.w = (float)h[3] + (float)l[3];
#pragma unroll 4
  for (int t = 1; t < 64; ++t) {
    size_t off = (size_t)t * BD + i;
    h = *(const f16x4*)(hi + off);
    l = *(const f16x4*)(lo + off);
    float4 wv = *(const float4*)(w + off - BD);
    a.x += ((float)h[0] + (float)l[0]) * wv.x;
    a.y += ((float)h[1] + (float)l[1]) * wv.y;
    a.z += ((float)h[2] + (float)l[2]) * wv.z;
    a.w += ((float)h[3] + (float)l[3]) * wv.w;
  }
  *(float4*)(out + i) = a;
}

extern "C" void kernel_launch(void* const* d_in, const int* in_sizes, int n_in,
                              void* d_out, int out_size, void* d_ws, size_t ws_size,
                              hipStream_t stream) {
  const float* pred = (const float*)d_in[0];
  const float* tru  = (const float*)d_in[1];
  const float* W    = (const float*)d_in[2];
  const float* bias = (const float*)d_in[3];
  float* out = (float*)d_out;

  char* ws = (char*)d_ws;
  _Float16* se_hi  = (_Float16*)(ws);                    // 128 MB
  _Float16* se_lo  = (_Float16*)(ws + 134217728ull);     // 128 MB
  float*    logits = (float*)   (ws + 268435456ull);     // 256 MB (reused as weight)
  _Float16* W_hi   = (_Float16*)(ws + 536870912ull);     // 2 MB
  _Float16* W_lo   = (_Float16*)(ws + 538968064ull);     // 2 MB

  se_split_k<<<2048, 256, 0, stream>>>(pred, tru, se_hi, se_lo);
  w_split_k<<<1024, 256, 0, stream>>>(W, W_hi, W_lo);
  gemm_logits_k<<<4096, 256, 0, stream>>>(se_hi, se_lo, W_hi, W_lo, bias, logits);
  softmax_w_k<<<65536, 256, 0, stream>>>(logits, se_hi, se_lo);
  loss_k<<<1024, 256, 0, stream>>>(se_hi, se_lo, logits, out);
}

// Round 2
// 786.413 us; speedup vs baseline: 1.1345x; 1.1345x over previous
//
#include <hip/hip_runtime.h>
#include <hip/hip_fp16.h>

typedef _Float16 f16x4 __attribute__((ext_vector_type(4)));
typedef _Float16 f16x8 __attribute__((ext_vector_type(8)));
typedef float    f32x4 __attribute__((ext_vector_type(4)));

#define TBD 67108864ull   // T*B*D
#define BD  1048576ull    // B*D

#define ASM_VMCNT(N) asm volatile("s_waitcnt vmcnt(" #N ")" ::: "memory")
#define ASM_LGKM(N)  asm volatile("s_waitcnt lgkmcnt(" #N ")" ::: "memory")
#define BARRIER()    __builtin_amdgcn_s_barrier()
#define MFMA(a,b,c)  __builtin_amdgcn_mfma_f32_16x16x32_f16((a),(b),(c),0,0,0)

// ---------------- Kernel 1: se = (pred-true)^2, split into fp16 hi/lo ----------------
__global__ __launch_bounds__(256) void se_split_k(const float* __restrict__ pred,
                                                  const float* __restrict__ tru,
                                                  _Float16* __restrict__ hi,
                                                  _Float16* __restrict__ lo) {
  size_t stride = (size_t)gridDim.x * 1024;
  for (size_t i = ((size_t)blockIdx.x * 256 + threadIdx.x) * 4; i < TBD; i += stride) {
    float4 p = *(const float4*)(pred + i);
    float4 t = *(const float4*)(tru + i);
    float s0 = (p.x - t.x) * (p.x - t.x);
    float s1 = (p.y - t.y) * (p.y - t.y);
    float s2 = (p.z - t.z) * (p.z - t.z);
    float s3 = (p.w - t.w) * (p.w - t.w);
    f16x4 h, l;
    h[0] = (_Float16)s0; l[0] = (_Float16)(s0 - (float)h[0]);
    h[1] = (_Float16)s1; l[1] = (_Float16)(s1 - (float)h[1]);
    h[2] = (_Float16)s2; l[2] = (_Float16)(s2 - (float)h[2]);
    h[3] = (_Float16)s3; l[3] = (_Float16)(s3 - (float)h[3]);
    *(f16x4*)(hi + i) = h;
    *(f16x4*)(lo + i) = l;
  }
}

// ---------------- Kernel 2: split W into fp16 hi/lo ----------------
__global__ __launch_bounds__(256) void w_split_k(const float* __restrict__ W,
                                                 _Float16* __restrict__ hi,
                                                 _Float16* __restrict__ lo) {
  size_t i = ((size_t)blockIdx.x * 256 + threadIdx.x) * 4;  // covers 1048576 exactly
  float4 x = *(const float4*)(W + i);
  f16x4 h, l;
  h[0] = (_Float16)x.x; l[0] = (_Float16)(x.x - (float)h[0]);
  h[1] = (_Float16)x.y; l[1] = (_Float16)(x.y - (float)h[1]);
  h[2] = (_Float16)x.z; l[2] = (_Float16)(x.z - (float)h[2]);
  h[3] = (_Float16)x.w; l[3] = (_Float16)(x.w - (float)h[3]);
  *(f16x4*)(hi + i) = h;
  *(f16x4*)(lo + i) = l;
}

// ---------------- Kernel 3: logits = SE @ W^T + b (split-fp16 3-pass, 256x256 pipelined) ---
// M=65536, N=1024, K=1024. Tile 256x256, BK=32, 8 waves (2M x 4N), per-wave 128x64.
// LDS: 2 buffers x 64KB; each buffer = A[256 rows][128B] + B[256 rows][128B].
// Row = 8 x 16B slots: slots 0-3 = hi(k0..31), 4-7 = lo; physical slot = logical ^ (row&7).
// Pipeline: 2-deep prefetch via global_load_lds; counted vmcnt(8); raw barriers.
#define PHASE_READS(fi0, AH0, AL0, AH1, AL1)                     \
  AH0 = *(const f16x8*)(ldsb + aoffH + (fi0) * 2048);            \
  AL0 = *(const f16x8*)(ldsb + aoffL + (fi0) * 2048);            \
  AH1 = *(const f16x8*)(ldsb + aoffH + (fi0 + 1) * 2048);        \
  AL1 = *(const f16x8*)(ldsb + aoffL + (fi0 + 1) * 2048);

#define PHASE_MFMA(fi0, AH0, AL0, AH1, AL1)                      \
  __builtin_amdgcn_s_setprio(1);                                 \
  _Pragma("unroll")                                              \
  for (int fj = 0; fj < 4; ++fj) {                               \
    acc[fi0][fj]     = MFMA(AH0, bh[fj], acc[fi0][fj]);          \
    acc[fi0][fj]     = MFMA(AL0, bh[fj], acc[fi0][fj]);          \
    acc[fi0][fj]     = MFMA(AH0, bl[fj], acc[fi0][fj]);          \
    acc[fi0 + 1][fj] = MFMA(AH1, bh[fj], acc[fi0 + 1][fj]);      \
    acc[fi0 + 1][fj] = MFMA(AL1, bh[fj], acc[fi0 + 1][fj]);      \
    acc[fi0 + 1][fj] = MFMA(AH1, bl[fj], acc[fi0 + 1][fj]);      \
  }                                                              \
  __builtin_amdgcn_s_setprio(0);

__global__ __launch_bounds__(512, 2) void gemm_logits_k(
    const _Float16* __restrict__ Ah, const _Float16* __restrict__ Al,
    const _Float16* __restrict__ Wh, const _Float16* __restrict__ Wl,
    const float* __restrict__ bias, float* __restrict__ C) {
  __shared__ uint4 lds4[8192];  // 128 KiB
  char* lds = (char*)lds4;
  const int tid = threadIdx.x;
  const int lane = tid & 63;
  const int wid = tid >> 6;          // 0..7
  const int wr = wid >> 2;           // 0..1 (M)
  const int wc = wid & 3;            // 0..3 (N)

  // XCD-aware bijective swizzle: 1024 blocks, 8 XCDs, 128 per XCD.
  const int bid = blockIdx.x;
  const int wgid = (bid & 7) * 128 + (bid >> 3);
  const int bm = wgid >> 2, bn = wgid & 3;   // 256 M-tiles x 4 N-tiles
  const int row0 = bm * 256, col0 = bn * 256;

  // Staging source addresses (inverse-swizzled), 4 A + 4 B chunks of 16B per thread.
  const _Float16* aSrc[4];
  const _Float16* bSrc[4];
#pragma unroll
  for (int q = 0; q < 4; ++q) {
    int p = q * 8192 + tid * 16;      // byte offset in 32KB region
    int r = p >> 7;                   // row 0..255
    int s = (p >> 4) & 7;             // physical slot
    int sig = s ^ (r & 7);            // logical slot
    size_t koff = (size_t)(sig & 3) * 8;
    aSrc[q] = (sig < 4 ? Ah : Al) + ((size_t)(row0 + r) * 1024 + koff);
    bSrc[q] = (sig < 4 ? Wh : Wl) + ((size_t)(col0 + r) * 1024 + koff);
  }

  // Fragment read offsets (within a buffer).
  const int u = lane >> 4;           // 0..3 -> k = 8u
  const int sw = lane & 7;
  const int aRow = wr * 128 + (lane & 15);
  const int bRow = wc * 64 + (lane & 15);
  const int aoffH = aRow * 128 + ((u)     ^ sw) * 16;
  const int aoffL = aRow * 128 + ((u + 4) ^ sw) * 16;
  const int boffH = 32768 + bRow * 128 + ((u)     ^ sw) * 16;
  const int boffL = 32768 + bRow * 128 + ((u + 4) ^ sw) * 16;

  f32x4 acc[8][4] = {};

  // Prologue: stage tile 0 -> buf0, tile 1 -> buf1.
#pragma unroll
  for (int q = 0; q < 4; ++q) {
    __builtin_amdgcn_global_load_lds(
        (const __attribute__((address_space(1))) void*)(aSrc[q]),
        (__attribute__((address_space(3))) void*)(lds + q * 8192 + tid * 16), 16, 0, 0);
    __builtin_amdgcn_global_load_lds(
        (const __attribute__((address_space(1))) void*)(bSrc[q]),
        (__attribute__((address_space(3))) void*)(lds + 32768 + q * 8192 + tid * 16), 16, 0, 0);
  }
#pragma unroll
  for (int q = 0; q < 4; ++q) {
    __builtin_amdgcn_global_load_lds(
        (const __attribute__((address_space(1))) void*)(aSrc[q] + 32),
        (__attribute__((address_space(3))) void*)(lds + 65536 + q * 8192 + tid * 16), 16, 0, 0);
    __builtin_amdgcn_global_load_lds(
        (const __attribute__((address_space(1))) void*)(bSrc[q] + 32),
        (__attribute__((address_space(3))) void*)(lds + 65536 + 32768 + q * 8192 + tid * 16), 16, 0, 0);
  }
  ASM_VMCNT(8);   // tile 0 resident
  BARRIER();

#pragma unroll 1
  for (int t = 0; t < 32; ++t) {
    char* ldsb = lds + (t & 1) * 65536;
    // B fragments (resident for the whole K-step)
    f16x8 bh[4], bl[4];
#pragma unroll
    for (int fj = 0; fj < 4; ++fj) {
      bh[fj] = *(const f16x8*)(ldsb + boffH + fj * 2048);
      bl[fj] = *(const f16x8*)(ldsb + boffL + fj * 2048);
    }
    f16x8 a0h, a0l, a1h, a1l;
    PHASE_READS(0, a0h, a0l, a1h, a1l)
    f16x8 a2h, a2l, a3h, a3l;
    PHASE_READS(2, a2h, a2l, a3h, a3l)
    ASM_LGKM(4);                       // B + A01 ready (A23 in flight)
    PHASE_MFMA(0, a0h, a0l, a1h, a1l)
    f16x8 a4h, a4l, a5h, a5l;
    PHASE_READS(4, a4h, a4l, a5h, a5l)
    ASM_LGKM(4);                       // A23 ready
    PHASE_MFMA(2, a2h, a2l, a3h, a3l)
    f16x8 a6h, a6l, a7h, a7l;
    PHASE_READS(6, a6h, a6l, a7h, a7l)
    ASM_LGKM(4);                       // A45 ready
    PHASE_MFMA(4, a4h, a4l, a5h, a5l)
    ASM_LGKM(0);                       // all reads of this buffer done
    BARRIER();                         // every wave done reading buf[t&1]
    // Stage tile t+2 into buf[t&1] (dummy reload near the tail keeps vmcnt uniform).
    {
      int tt = (t + 2 < 32) ? t + 2 : 31;
      size_t kof = (size_t)tt * 32;
      int lbase = (t & 1) * 65536;
#pragma unroll
      for (int q = 0; q < 4; ++q) {
        __builtin_amdgcn_global_load_lds(
            (const __attribute__((address_space(1))) void*)(aSrc[q] + kof),
            (__attribute__((address_space(3))) void*)(lds + lbase + q * 8192 + tid * 16), 16, 0, 0);
        __builtin_amdgcn_global_load_lds(
            (const __attribute__((address_space(1))) void*)(bSrc[q] + kof),
            (__attribute__((address_space(3))) void*)(lds + lbase + 32768 + q * 8192 + tid * 16), 16, 0, 0);
      }
    }
    PHASE_MFMA(6, a6h, a6l, a7h, a7l)
    ASM_VMCNT(8);                      // next tile (t+1) fully landed
    BARRIER();
  }
  ASM_VMCNT(0);                        // drain dummy loads before LDS goes away

  // Epilogue: C[i,j] = acc + bias[j].  C/D: col=lane&15, row=(lane>>4)*4+q.
#pragma unroll
  for (int fj = 0; fj < 4; ++fj) {
    int c = col0 + wc * 64 + fj * 16 + (lane & 15);
    float bj = bias[c];
#pragma unroll
    for (int fi = 0; fi < 8; ++fi) {
      int r = row0 + wr * 128 + fi * 16 + u * 4;
#pragma unroll
      for (int q = 0; q < 4; ++q)
        C[(size_t)(r + q) * 1024 + c] = acc[fi][fj][q] + bj;
    }
  }
}

// ---------------- Kernel 4: row softmax + weight = se * softmax(logits), in-place ----------------
__global__ __launch_bounds__(256) void softmax_w_k(float* __restrict__ logits,
                                                   const _Float16* __restrict__ hi,
                                                   const _Float16* __restrict__ lo) {
  const int row = blockIdx.x;            // 0..65535 (t*B+b)
  const size_t base = (size_t)row * 1024;
  const int tid = threadIdx.x, lane = tid & 63, wid = tid >> 6;
  float4 x = ((const float4*)(logits + base))[tid];
  float m = fmaxf(fmaxf(x.x, x.y), fmaxf(x.z, x.w));
#pragma unroll
  for (int o = 32; o >= 1; o >>= 1) m = fmaxf(m, __shfl_xor(m, o, 64));
  __shared__ float red[8];
  if (lane == 0) red[wid] = m;
  __syncthreads();
  m = fmaxf(fmaxf(red[0], red[1]), fmaxf(red[2], red[3]));
  float e0 = __expf(x.x - m), e1 = __expf(x.y - m), e2 = __expf(x.z - m), e3 = __expf(x.w - m);
  float s = (e0 + e1) + (e2 + e3);
#pragma unroll
  for (int o = 32; o >= 1; o >>= 1) s += __shfl_xor(s, o, 64);
  if (lane == 0) red[4 + wid] = s;
  __syncthreads();
  s = (red[4] + red[5]) + (red[6] + red[7]);
  float inv = 1.0f / s;
  f16x4 h = ((const f16x4*)(hi + base))[tid];
  f16x4 l = ((const f16x4*)(lo + base))[tid];
  float4 w;
  w.x = ((float)h[0] + (float)l[0]) * e0 * inv;
  w.y = ((float)h[1] + (float)l[1]) * e1 * inv;
  w.z = ((float)h[2] + (float)l[2]) * e2 * inv;
  w.w = ((float)h[3] + (float)l[3]) * e3 * inv;
  ((float4*)(logits + base))[tid] = w;
}

// ---------------- Kernel 5: loss[b,d] = se_0 + sum_{t=1..63} w_{t-1} * se_t ----------------
__global__ __launch_bounds__(256) void loss_k(const _Float16* __restrict__ hi,
                                              const _Float16* __restrict__ lo,
                                              const float* __restrict__ w,
                                              float* __restrict__ out) {
  size_t i = ((size_t)blockIdx.x * 256 + threadIdx.x) * 4;  // over B*D
  f16x4 h = *(const f16x4*)(hi + i);
  f16x4 l = *(const f16x4*)(lo + i);
  float4 a;
  a.x = (float)h[0] + (float)l[0];
  a.y = (float)h[1] + (float)l[1];
  a.z = (float)h[2] + (float)l[2];
  a.w = (float)h[3] + (float)l[3];
#pragma unroll 4
  for (int t = 1; t < 64; ++t) {
    size_t off = (size_t)t * BD + i;
    h = *(const f16x4*)(hi + off);
    l = *(const f16x4*)(lo + off);
    float4 wv = *(const float4*)(w + off - BD);
    a.x += ((float)h[0] + (float)l[0]) * wv.x;
    a.y += ((float)h[1] + (float)l[1]) * wv.y;
    a.z += ((float)h[2] + (float)l[2]) * wv.z;
    a.w += ((float)h[3] + (float)l[3]) * wv.w;
  }
  *(float4*)(out + i) = a;
}

extern "C" void kernel_launch(void* const* d_in, const int* in_sizes, int n_in,
                              void* d_out, int out_size, void* d_ws, size_t ws_size,
                              hipStream_t stream) {
  const float* pred = (const float*)d_in[0];
  const float* tru  = (const float*)d_in[1];
  const float* W    = (const float*)d_in[2];
  const float* bias = (const float*)d_in[3];
  float* out = (float*)d_out;

  char* ws = (char*)d_ws;
  _Float16* se_hi  = (_Float16*)(ws);                    // 128 MB
  _Float16* se_lo  = (_Float16*)(ws + 134217728ull);     // 128 MB
  float*    logits = (float*)   (ws + 268435456ull);     // 256 MB (reused as weight)
  _Float16* W_hi   = (_Float16*)(ws + 536870912ull);     // 2 MB
  _Float16* W_lo   = (_Float16*)(ws + 538968064ull);     // 2 MB

  se_split_k<<<2048, 256, 0, stream>>>(pred, tru, se_hi, se_lo);
  w_split_k<<<1024, 256, 0, stream>>>(W, W_hi, W_lo);
  gemm_logits_k<<<1024, 512, 0, stream>>>(se_hi, se_lo, W_hi, W_lo, bias, logits);
  softmax_w_k<<<65536, 256, 0, stream>>>(logits, se_hi, se_lo);
  loss_k<<<1024, 256, 0, stream>>>(se_hi, se_lo, logits, out);
}

// Round 3
// 630.031 us; speedup vs baseline: 1.4161x; 1.2482x over previous
//
#include <hip/hip_runtime.h>
#include <hip/hip_fp16.h>

typedef _Float16 f16x4 __attribute__((ext_vector_type(4)));
typedef _Float16 f16x8 __attribute__((ext_vector_type(8)));
typedef float    f32x4 __attribute__((ext_vector_type(4)));

#define TBD 67108864ull   // T*B*D
#define BD  1048576ull    // B*D

#define ASM_VMCNT(N) asm volatile("s_waitcnt vmcnt(" #N ")" ::: "memory")
#define ASM_LGKM(N)  asm volatile("s_waitcnt lgkmcnt(" #N ")" ::: "memory")
#define BARRIER()    __builtin_amdgcn_s_barrier()
#define MFMA(a,b,c)  __builtin_amdgcn_mfma_f32_16x16x32_f16((a),(b),(c),0,0,0)

// ---------------- Kernel 1: se = (pred-true)^2, split into fp16 hi/lo ----------------
__global__ __launch_bounds__(256) void se_split_k(const float* __restrict__ pred,
                                                  const float* __restrict__ tru,
                                                  _Float16* __restrict__ hi,
                                                  _Float16* __restrict__ lo) {
  size_t stride = (size_t)gridDim.x * 1024;
  for (size_t i = ((size_t)blockIdx.x * 256 + threadIdx.x) * 4; i < TBD; i += stride) {
    float4 p = *(const float4*)(pred + i);
    float4 t = *(const float4*)(tru + i);
    float s0 = (p.x - t.x) * (p.x - t.x);
    float s1 = (p.y - t.y) * (p.y - t.y);
    float s2 = (p.z - t.z) * (p.z - t.z);
    float s3 = (p.w - t.w) * (p.w - t.w);
    f16x4 h, l;
    h[0] = (_Float16)s0; l[0] = (_Float16)(s0 - (float)h[0]);
    h[1] = (_Float16)s1; l[1] = (_Float16)(s1 - (float)h[1]);
    h[2] = (_Float16)s2; l[2] = (_Float16)(s2 - (float)h[2]);
    h[3] = (_Float16)s3; l[3] = (_Float16)(s3 - (float)h[3]);
    *(f16x4*)(hi + i) = h;
    *(f16x4*)(lo + i) = l;
  }
}

// ---------------- Kernel 2: split W into fp16 hi/lo ----------------
__global__ __launch_bounds__(256) void w_split_k(const float* __restrict__ W,
                                                 _Float16* __restrict__ hi,
                                                 _Float16* __restrict__ lo) {
  size_t i = ((size_t)blockIdx.x * 256 + threadIdx.x) * 4;  // covers 1048576 exactly
  float4 x = *(const float4*)(W + i);
  f16x4 h, l;
  h[0] = (_Float16)x.x; l[0] = (_Float16)(x.x - (float)h[0]);
  h[1] = (_Float16)x.y; l[1] = (_Float16)(x.y - (float)h[1]);
  h[2] = (_Float16)x.z; l[2] = (_Float16)(x.z - (float)h[2]);
  h[3] = (_Float16)x.w; l[3] = (_Float16)(x.w - (float)h[3]);
  *(f16x4*)(hi + i) = h;
  *(f16x4*)(lo + i) = l;
}

// ---------------- Kernel 3: logits = SE @ W^T + b (split-fp16 3-pass, 256x256 pipelined) ---
// M=65536, N=1024, K=1024. Tile 256x256, BK=32, 8 waves (2M x 4N), per-wave 128x64.
// LDS: 2 buffers x 64KB; each buffer = A[256 rows][128B] + B[256 rows][128B].
// Row = 8 x 16B slots: slots 0-3 = hi(k0..31), 4-7 = lo; physical slot = logical ^ (row&7).
// Pipeline: 2-deep prefetch via global_load_lds; counted vmcnt(8); raw barriers.
#define PHASE_READS(fi0, AH0, AL0, AH1, AL1)                     \
  AH0 = *(const f16x8*)(ldsb + aoffH + (fi0) * 2048);            \
  AL0 = *(const f16x8*)(ldsb + aoffL + (fi0) * 2048);            \
  AH1 = *(const f16x8*)(ldsb + aoffH + (fi0 + 1) * 2048);        \
  AL1 = *(const f16x8*)(ldsb + aoffL + (fi0 + 1) * 2048);

// Pass-major MFMA ordering: 8 independent accumulators between any reuse
// (dep-chain fix: round-2 order had 3-deep dependent chains per acc).
#define MFMA_CLUSTER(f0, A0H, A0L, A1H, A1L)                     \
  __builtin_amdgcn_s_setprio(1);                                 \
  _Pragma("unroll")                                              \
  for (int fj = 0; fj < 4; ++fj) {                               \
    acc[f0][fj]     = MFMA(A0H, bh[fj], acc[f0][fj]);            \
    acc[f0 + 1][fj] = MFMA(A1H, bh[fj], acc[f0 + 1][fj]);        \
  }                                                              \
  _Pragma("unroll")                                              \
  for (int fj = 0; fj < 4; ++fj) {                               \
    acc[f0][fj]     = MFMA(A0L, bh[fj], acc[f0][fj]);            \
    acc[f0 + 1][fj] = MFMA(A1L, bh[fj], acc[f0 + 1][fj]);        \
  }                                                              \
  _Pragma("unroll")                                              \
  for (int fj = 0; fj < 4; ++fj) {                               \
    acc[f0][fj]     = MFMA(A0H, bl[fj], acc[f0][fj]);            \
    acc[f0 + 1][fj] = MFMA(A1H, bl[fj], acc[f0 + 1][fj]);        \
  }                                                              \
  __builtin_amdgcn_s_setprio(0);

__global__ __launch_bounds__(512, 2) void gemm_logits_k(
    const _Float16* __restrict__ Ah, const _Float16* __restrict__ Al,
    const _Float16* __restrict__ Wh, const _Float16* __restrict__ Wl,
    const float* __restrict__ bias, float* __restrict__ C) {
  __shared__ uint4 lds4[8192];  // 128 KiB
  char* lds = (char*)lds4;
  const int tid = threadIdx.x;
  const int lane = tid & 63;
  const int wid = tid >> 6;          // 0..7
  const int wr = wid >> 2;           // 0..1 (M)
  const int wc = wid & 3;            // 0..3 (N)

  // XCD-aware bijective swizzle: 1024 blocks, 8 XCDs, 128 per XCD.
  const int bid = blockIdx.x;
  const int wgid = (bid & 7) * 128 + (bid >> 3);
  const int bm = wgid >> 2, bn = wgid & 3;   // 256 M-tiles x 4 N-tiles
  const int row0 = bm * 256, col0 = bn * 256;

  // Staging source addresses (inverse-swizzled), 4 A + 4 B chunks of 16B per thread.
  const _Float16* aSrc[4];
  const _Float16* bSrc[4];
#pragma unroll
  for (int q = 0; q < 4; ++q) {
    int p = q * 8192 + tid * 16;      // byte offset in 32KB region
    int r = p >> 7;                   // row 0..255
    int s = (p >> 4) & 7;             // physical slot
    int sig = s ^ (r & 7);            // logical slot
    size_t koff = (size_t)(sig & 3) * 8;
    aSrc[q] = (sig < 4 ? Ah : Al) + ((size_t)(row0 + r) * 1024 + koff);
    bSrc[q] = (sig < 4 ? Wh : Wl) + ((size_t)(col0 + r) * 1024 + koff);
  }

  // Fragment read offsets (within a buffer).
  const int u = lane >> 4;           // 0..3 -> k = 8u
  const int sw = lane & 7;
  const int aRow = wr * 128 + (lane & 15);
  const int bRow = wc * 64 + (lane & 15);
  const int aoffH = aRow * 128 + ((u)     ^ sw) * 16;
  const int aoffL = aRow * 128 + ((u + 4) ^ sw) * 16;
  const int boffH = 32768 + bRow * 128 + ((u)     ^ sw) * 16;
  const int boffL = 32768 + bRow * 128 + ((u + 4) ^ sw) * 16;

  f32x4 acc[8][4] = {};

  // Prologue: stage tile 0 -> buf0, tile 1 -> buf1.
#pragma unroll
  for (int q = 0; q < 4; ++q) {
    __builtin_amdgcn_global_load_lds(
        (const __attribute__((address_space(1))) void*)(aSrc[q]),
        (__attribute__((address_space(3))) void*)(lds + q * 8192 + tid * 16), 16, 0, 0);
    __builtin_amdgcn_global_load_lds(
        (const __attribute__((address_space(1))) void*)(bSrc[q]),
        (__attribute__((address_space(3))) void*)(lds + 32768 + q * 8192 + tid * 16), 16, 0, 0);
  }
#pragma unroll
  for (int q = 0; q < 4; ++q) {
    __builtin_amdgcn_global_load_lds(
        (const __attribute__((address_space(1))) void*)(aSrc[q] + 32),
        (__attribute__((address_space(3))) void*)(lds + 65536 + q * 8192 + tid * 16), 16, 0, 0);
    __builtin_amdgcn_global_load_lds(
        (const __attribute__((address_space(1))) void*)(bSrc[q] + 32),
        (__attribute__((address_space(3))) void*)(lds + 65536 + 32768 + q * 8192 + tid * 16), 16, 0, 0);
  }

#pragma unroll 1
  for (int t = 0; t < 32; ++t) {
    char* ldsb = lds + (t & 1) * 65536;
    ASM_VMCNT(8);                      // tile t fully resident (t+1's 8 loads may fly)
    BARRIER();
    // B fragments (resident for the whole K-step) + A01, A23
    f16x8 bh[4], bl[4];
#pragma unroll
    for (int fj = 0; fj < 4; ++fj) {
      bh[fj] = *(const f16x8*)(ldsb + boffH + fj * 2048);
      bl[fj] = *(const f16x8*)(ldsb + boffL + fj * 2048);
    }
    f16x8 a0h, a0l, a1h, a1l;
    PHASE_READS(0, a0h, a0l, a1h, a1l)
    f16x8 a2h, a2l, a3h, a3l;
    PHASE_READS(2, a2h, a2l, a3h, a3l)
    ASM_LGKM(4);                       // B + A01 ready (A23 in flight)
    MFMA_CLUSTER(0, a0h, a0l, a1h, a1l)
    f16x8 a4h, a4l, a5h, a5l;
    PHASE_READS(4, a4h, a4l, a5h, a5l)
    ASM_LGKM(4);                       // A23 ready
    MFMA_CLUSTER(2, a2h, a2l, a3h, a3l)
    f16x8 a6h, a6l, a7h, a7l;
    PHASE_READS(6, a6h, a6l, a7h, a7l)
    ASM_LGKM(4);                       // A45 ready
    MFMA_CLUSTER(4, a4h, a4l, a5h, a5l)
    ASM_LGKM(0);                       // all LDS reads of this buffer done
    BARRIER();                         // every wave done reading buf[t&1]
    // Stage tile t+2 into buf[t&1] (dummy reload near the tail keeps vmcnt uniform).
    {
      int tt = (t + 2 < 32) ? t + 2 : 31;
      size_t kof = (size_t)tt * 32;
      int lbase = (t & 1) * 65536;
#pragma unroll
      for (int q = 0; q < 4; ++q) {
        __builtin_amdgcn_global_load_lds(
            (const __attribute__((address_space(1))) void*)(aSrc[q] + kof),
            (__attribute__((address_space(3))) void*)(lds + lbase + q * 8192 + tid * 16), 16, 0, 0);
        __builtin_amdgcn_global_load_lds(
            (const __attribute__((address_space(1))) void*)(bSrc[q] + kof),
            (__attribute__((address_space(3))) void*)(lds + lbase + 32768 + q * 8192 + tid * 16), 16, 0, 0);
      }
    }
    MFMA_CLUSTER(6, a6h, a6l, a7h, a7l)
  }
  ASM_VMCNT(0);                        // drain dummy loads before LDS goes away

  // Epilogue: C[i,j] = acc + bias[j].  C/D: col=lane&15, row=(lane>>4)*4+q.
#pragma unroll
  for (int fj = 0; fj < 4; ++fj) {
    int c = col0 + wc * 64 + fj * 16 + (lane & 15);
    float bj = bias[c];
#pragma unroll
    for (int fi = 0; fi < 8; ++fi) {
      int r = row0 + wr * 128 + fi * 16 + u * 4;
#pragma unroll
      for (int q = 0; q < 4; ++q)
        C[(size_t)(r + q) * 1024 + c] = acc[fi][fj][q] + bj;
    }
  }
}

// ---------------- Kernel 4: fused softmax + gating + loss accumulation ----------------
// Block = batch row b. Loops t=0..63 keeping w_prev (gating weight) and loss acc in regs.
// loss[b,:] = se_0 + sum_{t=1..63} w_{t-1} * se_t ;  w_t = se_t * softmax(logits_t)
// Saves the 256MB w-write + 252MB w-read of the unfused version.
__global__ __launch_bounds__(256) void softmax_loss_k(const float* __restrict__ logits,
                                                      const _Float16* __restrict__ hi,
                                                      const _Float16* __restrict__ lo,
                                                      float* __restrict__ out) {
  const int b = blockIdx.x;            // 0..1023
  const int tid = threadIdx.x, lane = tid & 63, wid = tid >> 6;
  __shared__ float red[8];
  float4 wprev = make_float4(1.f, 1.f, 1.f, 1.f);
  float4 lacc  = make_float4(0.f, 0.f, 0.f, 0.f);

  size_t base = (size_t)b * 1024;      // row (t=0, b)
  float4 x = ((const float4*)(logits + base))[tid];
  f16x4  h = ((const f16x4*)(hi + base))[tid];
  f16x4  l = ((const f16x4*)(lo + base))[tid];

#pragma unroll 1
  for (int t = 0; t < 64; ++t) {
    // se_t and loss accumulation with w_{t-1}
    float4 se;
    se.x = (float)h[0] + (float)l[0];
    se.y = (float)h[1] + (float)l[1];
    se.z = (float)h[2] + (float)l[2];
    se.w = (float)h[3] + (float)l[3];
    lacc.x += wprev.x * se.x;
    lacc.y += wprev.y * se.y;
    lacc.z += wprev.z * se.z;
    lacc.w += wprev.w * se.w;

    // prefetch next row (T14: hide HBM latency under the softmax reduces)
    int tn = (t + 1 < 64) ? t + 1 : t;
    size_t nbase = ((size_t)tn * 1024 + (size_t)b) * 1024;
    float4 xn = ((const float4*)(logits + nbase))[tid];
    f16x4  hn = ((const f16x4*)(hi + nbase))[tid];
    f16x4  ln = ((const f16x4*)(lo + nbase))[tid];

    // row softmax on x
    float m = fmaxf(fmaxf(x.x, x.y), fmaxf(x.z, x.w));
#pragma unroll
    for (int o = 32; o >= 1; o >>= 1) m = fmaxf(m, __shfl_xor(m, o, 64));
    if (lane == 0) red[wid] = m;
    __syncthreads();
    m = fmaxf(fmaxf(red[0], red[1]), fmaxf(red[2], red[3]));
    float e0 = __expf(x.x - m), e1 = __expf(x.y - m), e2 = __expf(x.z - m), e3 = __expf(x.w - m);
    float s = (e0 + e1) + (e2 + e3);
#pragma unroll
    for (int o = 32; o >= 1; o >>= 1) s += __shfl_xor(s, o, 64);
    if (lane == 0) red[4 + wid] = s;
    __syncthreads();
    s = (red[4] + red[5]) + (red[6] + red[7]);
    float inv = 1.0f / s;

    wprev.x = se.x * e0 * inv;
    wprev.y = se.y * e1 * inv;
    wprev.z = se.z * e2 * inv;
    wprev.w = se.w * e3 * inv;

    x = xn; h = hn; l = ln;
  }
  ((float4*)(out + (size_t)b * 1024))[tid] = lacc;
}

extern "C" void kernel_launch(void* const* d_in, const int* in_sizes, int n_in,
                              void* d_out, int out_size, void* d_ws, size_t ws_size,
                              hipStream_t stream) {
  const float* pred = (const float*)d_in[0];
  const float* tru  = (const float*)d_in[1];
  const float* W    = (const float*)d_in[2];
  const float* bias = (const float*)d_in[3];
  float* out = (float*)d_out;

  char* ws = (char*)d_ws;
  _Float16* se_hi  = (_Float16*)(ws);                    // 128 MB
  _Float16* se_lo  = (_Float16*)(ws + 134217728ull);     // 128 MB
  float*    logits = (float*)   (ws + 268435456ull);     // 256 MB
  _Float16* W_hi   = (_Float16*)(ws + 536870912ull);     // 2 MB
  _Float16* W_lo   = (_Float16*)(ws + 538968064ull);     // 2 MB

  se_split_k<<<2048, 256, 0, stream>>>(pred, tru, se_hi, se_lo);
  w_split_k<<<1024, 256, 0, stream>>>(W, W_hi, W_lo);
  gemm_logits_k<<<1024, 512, 0, stream>>>(se_hi, se_lo, W_hi, W_lo, bias, logits);
  softmax_loss_k<<<1024, 256, 0, stream>>>(logits, se_hi, se_lo, out);
}